// Round 4
// baseline (570.674 us; speedup 1.0000x reference)
//
#include <hip/hip_runtime.h>
#include <math.h>

#define D 128
#define B2D 256
#define NSEG 64
#define PSTRIDE 144   // floats per chunk-partial: [0]=m, [1]=s, [8..135]=acc[128]
#define MAXC 127      // max chunks per segment (combine shared-mem bound)
#define NEG (-1e30f)  // sentinel instead of -inf: avoids NaN in 2-level merges

// ---------------- segment offsets (edge_batch is sorted) ----------------
__global__ void k_ofs(const int* __restrict__ eb, int* __restrict__ seg_ofs, int E) {
    int e = blockIdx.x * blockDim.x + threadIdx.x;
    if (e >= E) return;
    int b = eb[e];
    if (e == 0) {
        for (int j = 0; j <= b; ++j) seg_ofs[j] = 0;
    } else {
        int p = eb[e - 1];
        if (p != b) for (int j = p + 1; j <= b; ++j) seg_ofs[j] = e;
    }
    if (e == E - 1) {
        for (int j = b + 1; j <= NSEG; ++j) seg_ofs[j] = E;
    }
}

// ---------------- iteration-1 LSTM: x=0,h=0,c=0 -> gates are pure bias ----------------
__global__ void k_lstm0(const float* __restrict__ b_ih, const float* __restrict__ b_hh,
                        float* __restrict__ h, float* __restrict__ c) {
    int b = blockIdx.x, t = threadIdx.x;   // 64 blocks x 128 threads
    float gi = b_ih[t]       + b_hh[t];
    float gf = b_ih[t + 128] + b_hh[t + 128]; (void)gf;  // c0=0: f-gate contributes nothing
    float gg = b_ih[t + 256] + b_hh[t + 256];
    float go = b_ih[t + 384] + b_hh[t + 384];
    float si = 1.f / (1.f + expf(-gi));
    float so = 1.f / (1.f + expf(-go));
    float cn = si * tanhf(gg);
    float hn = so * tanhf(cn);
    c[b * D + t] = cn;
    h[b * D + t] = hn;
}

// ---------------- fused single-pass: logits + online softmax + weighted accumulate --------
// One wave per chunk (chunks never cross segments). Each quarter-wave (16 lanes,
// 32B/lane = one 512B feat row) handles one edge; one butterfly shuffle inst
// serves all 4 edges of the wave simultaneously.
__global__ __launch_bounds__(256) void k_pass(
        const float* __restrict__ feat, const int* __restrict__ seg_ofs,
        const float* __restrict__ h, float* __restrict__ part) {
    __shared__ int s_ofs[NSEG + 1], s_pre[NSEG + 1], s_epw[NSEG];
    int tid = threadIdx.x;
    if (tid <= NSEG) s_ofs[tid] = seg_ofs[tid];
    __syncthreads();
    if (tid < NSEG) {
        int len = s_ofs[tid + 1] - s_ofs[tid];
        int e = 0;
        if (len > 0) {
            int t1 = (len + MAXC - 1) / MAXC;   // ceil(len/127)
            e = ((t1 + 7) >> 3) << 3;           // round up to multiple of 8
        }
        s_epw[tid] = e;
    }
    __syncthreads();
    if (tid == 0) {
        int acc = 0;
        for (int j = 0; j < NSEG; ++j) {
            s_pre[j] = acc;
            int len = s_ofs[j + 1] - s_ofs[j];
            int e = s_epw[j];
            acc += (e > 0) ? (len + e - 1) / e : 0;
        }
        s_pre[NSEG] = acc;
    }
    __syncthreads();

    int total = s_pre[NSEG];
    int wave = (blockIdx.x * blockDim.x + tid) >> 6;
    int nwaves = (gridDim.x * blockDim.x) >> 6;
    int lane = tid & 63;
    int qtr = lane >> 4;    // which edge of the 4 in flight
    int ql  = lane & 15;    // position within the 16-lane edge group

    for (int cid = wave; cid < total; cid += nwaves) {
        // binary search: largest b with s_pre[b] <= cid
        int lo = 0, hi = NSEG - 1;
        while (lo < hi) {
            int mid = (lo + hi + 1) >> 1;
            if (s_pre[mid] <= cid) lo = mid; else hi = mid - 1;
        }
        int b = lo;
        int e = s_epw[b];
        long s0 = (long)s_ofs[b] + (long)(cid - s_pre[b]) * e;
        long s1 = (long)s_ofs[b + 1];
        if (s0 + e < s1) s1 = s0 + e;
        int len = (int)(s1 - s0);

        // lane owns dims [ql*4, ql*4+4) and [64+ql*4, 64+ql*4+4)
        float4 qa = *(const float4*)(h + (size_t)b * D + ql * 4);
        float4 qb = *(const float4*)(h + (size_t)b * D + 64 + ql * 4);

        float m = NEG, ssum = 0.f;
        float4 aa = make_float4(0.f, 0.f, 0.f, 0.f);
        float4 ab = make_float4(0.f, 0.f, 0.f, 0.f);

        const float* base = feat + (size_t)(s0 + qtr) * D;
        int n4 = len >> 2, rem = len & 3;
        for (int i = 0; i < n4; ++i, base += 4 * D) {
            float4 fa = *(const float4*)(base + ql * 4);
            float4 fb = *(const float4*)(base + 64 + ql * 4);
            float p = fa.x * qa.x + fa.y * qa.y + fa.z * qa.z + fa.w * qa.w
                    + fb.x * qb.x + fb.y * qb.y + fb.z * qb.z + fb.w * qb.w;
            p += __shfl_xor(p, 8, 16);
            p += __shfl_xor(p, 4, 16);
            p += __shfl_xor(p, 2, 16);
            p += __shfl_xor(p, 1, 16);   // all 16 lanes hold this edge's logit
            if (p > m) {
                float sc = __expf(m - p);   // exp(NEG - p) underflows to 0 on first edge
                ssum *= sc;
                aa.x *= sc; aa.y *= sc; aa.z *= sc; aa.w *= sc;
                ab.x *= sc; ab.y *= sc; ab.z *= sc; ab.w *= sc;
                m = p;
            }
            float w = __expf(p - m);
            ssum += w;
            aa.x += w * fa.x; aa.y += w * fa.y; aa.z += w * fa.z; aa.w += w * fa.w;
            ab.x += w * fb.x; ab.y += w * fb.y; ab.z += w * fb.z; ab.w += w * fb.w;
        }
        if (rem) {   // one masked iteration for the last 1..3 edges
            bool valid = qtr < rem;
            float4 fa = make_float4(0.f, 0.f, 0.f, 0.f);
            float4 fb = make_float4(0.f, 0.f, 0.f, 0.f);
            if (valid) {
                fa = *(const float4*)(base + ql * 4);
                fb = *(const float4*)(base + 64 + ql * 4);
            }
            float p = fa.x * qa.x + fa.y * qa.y + fa.z * qa.z + fa.w * qa.w
                    + fb.x * qb.x + fb.y * qb.y + fb.z * qb.z + fb.w * qb.w;
            p += __shfl_xor(p, 8, 16);
            p += __shfl_xor(p, 4, 16);
            p += __shfl_xor(p, 2, 16);
            p += __shfl_xor(p, 1, 16);
            if (valid) {
                if (p > m) {
                    float sc = __expf(m - p);
                    ssum *= sc;
                    aa.x *= sc; aa.y *= sc; aa.z *= sc; aa.w *= sc;
                    ab.x *= sc; ab.y *= sc; ab.z *= sc; ab.w *= sc;
                    m = p;
                }
                float w = __expf(p - m);
                ssum += w;
                aa.x += w * fa.x; aa.y += w * fa.y; aa.z += w * fa.z; aa.w += w * fa.w;
                ab.x += w * fb.x; ab.y += w * fb.y; ab.z += w * fb.z; ab.w += w * fb.w;
            }
        }

        // merge the 4 quarter-wave states (xor 16, then xor 32)
        #pragma unroll
        for (int off = 16; off <= 32; off <<= 1) {
            float m_o = __shfl_xor(m, off, 64);
            float s_o = __shfl_xor(ssum, off, 64);
            float4 aa_o, ab_o;
            aa_o.x = __shfl_xor(aa.x, off, 64); aa_o.y = __shfl_xor(aa.y, off, 64);
            aa_o.z = __shfl_xor(aa.z, off, 64); aa_o.w = __shfl_xor(aa.w, off, 64);
            ab_o.x = __shfl_xor(ab.x, off, 64); ab_o.y = __shfl_xor(ab.y, off, 64);
            ab_o.z = __shfl_xor(ab.z, off, 64); ab_o.w = __shfl_xor(ab.w, off, 64);
            float nm = fmaxf(m, m_o);
            float ea = __expf(m - nm), eb = __expf(m_o - nm);  // NEG sentinel: exp(0)=1, s=0 -> safe
            ssum = ssum * ea + s_o * eb;
            aa.x = aa.x * ea + aa_o.x * eb; aa.y = aa.y * ea + aa_o.y * eb;
            aa.z = aa.z * ea + aa_o.z * eb; aa.w = aa.w * ea + aa_o.w * eb;
            ab.x = ab.x * ea + ab_o.x * eb; ab.y = ab.y * ea + ab_o.y * eb;
            ab.z = ab.z * ea + ab_o.z * eb; ab.w = ab.w * ea + ab_o.w * eb;
            m = nm;
        }

        float* dst = part + (size_t)cid * PSTRIDE;
        if (lane == 0) { dst[0] = m; dst[1] = ssum; }
        if (qtr == 0) {
            *(float4*)(dst + 8 + ql * 4) = aa;
            *(float4*)(dst + 8 + 64 + ql * 4) = ab;
        }
    }
}

// ---------------- combine(prev pass) fused with LSTM cell: one block per segment ----------
__global__ __launch_bounds__(512) void k_lstm_comb(
        const float* __restrict__ part, const int* __restrict__ seg_ofs,
        const float* __restrict__ w_ih, const float* __restrict__ w_hh,
        const float* __restrict__ b_ih, const float* __restrict__ b_hh,
        float* __restrict__ h, float* __restrict__ c) {
    int b = blockIdx.x, t = threadIdx.x;
    __shared__ int s_ofs[NSEG + 1];
    __shared__ int s_c0, s_nc;
    __shared__ float s_w[MAXC];
    __shared__ float red[128];
    __shared__ float s_x[B2D];     // [h_prev | readout]
    __shared__ float s_g[4 * D];

    if (t <= NSEG) s_ofs[t] = seg_ofs[t];
    if (t < D) s_x[t] = h[b * D + t];   // h_prev (= q half of q_star)
    __syncthreads();
    if (t == 0) {
        int acc = 0, myc0 = 0, mync = 0;
        for (int j = 0; j < NSEG; ++j) {
            int len = s_ofs[j + 1] - s_ofs[j];
            int cnt = 0;
            if (len > 0) {
                int t1 = (len + MAXC - 1) / MAXC;
                int e = ((t1 + 7) >> 3) << 3;
                cnt = (len + e - 1) / e;
            }
            if (j == b) { myc0 = acc; mync = cnt; }
            acc += cnt;
        }
        s_c0 = myc0; s_nc = mync;
    }
    __syncthreads();
    int c0 = s_c0, nc = s_nc;

    // combine pass 1: max of chunk maxima
    if (t < 128) {
        float M = (t < nc) ? part[(size_t)(c0 + t) * PSTRIDE] : NEG;
        red[t] = M;
    }
    __syncthreads();
    for (int o = 64; o > 0; o >>= 1) {
        if (t < o) red[t] = fmaxf(red[t], red[t + o]);
        __syncthreads();
    }
    float M = red[0];
    __syncthreads();
    // combine pass 2: chunk weights + rescaled sum
    if (t < 128) {
        float S = 0.f;
        if (t < nc) {
            const float* pe = part + (size_t)(c0 + t) * PSTRIDE;
            float w = __expf(pe[0] - M);
            s_w[t] = w;
            S = w * pe[1];
        }
        red[t] = S;
    }
    __syncthreads();
    for (int o = 64; o > 0; o >>= 1) {
        if (t < o) red[t] += red[t + o];
        __syncthreads();
    }
    float S = red[0];
    // combine pass 3: rescaled accumulator -> readout in s_x[128..]
    if (t < 128) {
        float R = 0.f;
        for (int cc = 0; cc < nc; ++cc)
            R += s_w[cc] * part[(size_t)(c0 + cc) * PSTRIDE + 8 + t];
        s_x[D + t] = R / (S + 1e-8f);
    }
    __syncthreads();

    // LSTM: gate t (order i|f|g|o), x = s_x[0:256], hidden = s_x[0:128]
    float acc = b_ih[t] + b_hh[t];
    const float* wr = w_ih + (size_t)t * B2D;
    #pragma unroll 8
    for (int k = 0; k < B2D; k += 4) {
        float4 w4 = *(const float4*)(wr + k);
        acc += w4.x * s_x[k] + w4.y * s_x[k + 1] + w4.z * s_x[k + 2] + w4.w * s_x[k + 3];
    }
    const float* wh = w_hh + (size_t)t * D;
    #pragma unroll 8
    for (int k = 0; k < D; k += 4) {
        float4 w4 = *(const float4*)(wh + k);
        acc += w4.x * s_x[k] + w4.y * s_x[k + 1] + w4.z * s_x[k + 2] + w4.w * s_x[k + 3];
    }
    s_g[t] = acc;
    __syncthreads();

    if (t < D) {
        float gi = s_g[t], gf = s_g[t + D], gg = s_g[t + 2 * D], go = s_g[t + 3 * D];
        float si = 1.f / (1.f + expf(-gi));
        float sf = 1.f / (1.f + expf(-gf));
        float so = 1.f / (1.f + expf(-go));
        float cn = sf * c[b * D + t] + si * tanhf(gg);
        float hn = so * tanhf(cn);
        c[b * D + t] = cn;
        h[b * D + t] = hn;
    }
}

// ---------------- final combine + output write: out[b] = [h3, readout3] ----------------
__global__ __launch_bounds__(128) void k_comb_out(
        const float* __restrict__ part, const int* __restrict__ seg_ofs,
        const float* __restrict__ h, float* __restrict__ out) {
    int b = blockIdx.x, t = threadIdx.x;   // 128 threads
    __shared__ int s_ofs[NSEG + 1];
    __shared__ int s_c0, s_nc;
    __shared__ float s_w[MAXC];
    __shared__ float red[128];

    if (t <= NSEG) s_ofs[t] = seg_ofs[t];
    if (t + 64 <= NSEG) s_ofs[t + 64] = seg_ofs[t + 64];
    __syncthreads();
    if (t == 0) {
        int acc = 0, myc0 = 0, mync = 0;
        for (int j = 0; j < NSEG; ++j) {
            int len = s_ofs[j + 1] - s_ofs[j];
            int cnt = 0;
            if (len > 0) {
                int t1 = (len + MAXC - 1) / MAXC;
                int e = ((t1 + 7) >> 3) << 3;
                cnt = (len + e - 1) / e;
            }
            if (j == b) { myc0 = acc; mync = cnt; }
            acc += cnt;
        }
        s_c0 = myc0; s_nc = mync;
    }
    __syncthreads();
    int c0 = s_c0, nc = s_nc;

    float M = (t < nc) ? part[(size_t)(c0 + t) * PSTRIDE] : NEG;
    red[t] = M;
    __syncthreads();
    for (int o = 64; o > 0; o >>= 1) {
        if (t < o) red[t] = fmaxf(red[t], red[t + o]);
        __syncthreads();
    }
    M = red[0];
    __syncthreads();
    float S = 0.f;
    if (t < nc) {
        const float* pe = part + (size_t)(c0 + t) * PSTRIDE;
        float w = __expf(pe[0] - M);
        s_w[t] = w;
        S = w * pe[1];
    }
    red[t] = S;
    __syncthreads();
    for (int o = 64; o > 0; o >>= 1) {
        if (t < o) red[t] += red[t + o];
        __syncthreads();
    }
    S = red[0];
    float R = 0.f;
    for (int cc = 0; cc < nc; ++cc)
        R += s_w[cc] * part[(size_t)(c0 + cc) * PSTRIDE + 8 + t];
    out[b * B2D + t] = h[b * D + t];             // q half = h3
    out[b * B2D + D + t] = R / (S + 1e-8f);      // readout half
}

extern "C" void kernel_launch(void* const* d_in, const int* in_sizes, int n_in,
                              void* d_out, int out_size, void* d_ws, size_t ws_size,
                              hipStream_t stream) {
    const float* feat = (const float*)d_in[0];
    const int*   eb   = (const int*)d_in[1];
    const float* w_ih = (const float*)d_in[2];
    const float* w_hh = (const float*)d_in[3];
    const float* b_ih = (const float*)d_in[4];
    const float* b_hh = (const float*)d_in[5];
    float* out = (float*)d_out;
    float* ws  = (float*)d_ws;
    const int E = in_sizes[1];   // 500000

    // workspace layout (float offsets); everything written before read (ws is poisoned)
    float* h    = ws;                  // 64*128
    float* c    = ws + 8192;           // 64*128
    int*   seg  = (int*)(ws + 16384);  // 65 ints
    float* part = ws + 16512;          // up to 64*127*144 floats (~4.7 MB)

    k_ofs<<<(E + 255) / 256, 256, 0, stream>>>(eb, seg, E);
    k_lstm0<<<NSEG, 128, 0, stream>>>(b_ih, b_hh, h, c);          // iteration-1 LSTM (bias only)

    const int BLOCKS = 2048, THREADS = 256;  // 8192 waves >= max 8128 chunks
    k_pass<<<BLOCKS, THREADS, 0, stream>>>(feat, seg, h, part);                    // pass 1
    k_lstm_comb<<<NSEG, 512, 0, stream>>>(part, seg, w_ih, w_hh, b_ih, b_hh, h, c); // -> h2
    k_pass<<<BLOCKS, THREADS, 0, stream>>>(feat, seg, h, part);                    // pass 2
    k_lstm_comb<<<NSEG, 512, 0, stream>>>(part, seg, w_ih, w_hh, b_ih, b_hh, h, c); // -> h3
    k_pass<<<BLOCKS, THREADS, 0, stream>>>(feat, seg, h, part);                    // pass 3
    k_comb_out<<<NSEG, 128, 0, stream>>>(part, seg, h, out);                       // [h3, readout3]
}